// Round 2
// baseline (17097.488 us; speedup 1.0000x reference)
//
#include <hip/hip_runtime.h>
#include <hip/hip_bf16.h>

#define T_STEPS 8192
#define HID 256
#define NWG 16        // workgroups; each owns 16 hidden units (64 gate rows)
#define THREADS 256   // 4 waves; lane=(row, k-quarter): 64 rows x 4 k-quarters

__device__ __forceinline__ float sigm(float x) { return 1.0f / (1.0f + __expf(-x)); }
// 2/(1+e^-2x)-1 is inf-safe at both ends (x->-inf: 2/inf-1=-1; x->+inf: 2/1-1=1)
__device__ __forceinline__ float tanh_fast(float x) { return 2.0f / (1.0f + __expf(-2.0f * x)) - 1.0f; }

__global__ __launch_bounds__(THREADS, 1)
void lstm_scan(const int* __restrict__ tokens,
               const float* __restrict__ emb,    // [V,256] fp32
               const float* __restrict__ Wih,    // [1024,256] fp32
               const float* __restrict__ Whh,    // [1024,256] fp32
               const float* __restrict__ bih,    // [1024]
               const float* __restrict__ bhh,    // [1024]
               float* __restrict__ out,          // [T*256 + 256 + 256] fp32
               unsigned long long* __restrict__ hbuf)  // [2][256] (h fp32, tag u32)
{
    const int tid  = threadIdx.x;
    const int w    = blockIdx.x;       // 0..15
    const int lane = tid & 63;
    const int wave = tid >> 6;         // 0..3
    const int rl   = lane >> 2;        // row-within-wave 0..15
    const int kq   = lane & 3;         // k-quarter 0..3
    const int r_wg = wave * 16 + rl;   // local gate-row 0..63
    const int unit_local = r_wg >> 2;  // 0..15
    const int gate = r_wg & 3;         // 0=i 1=f 2=cell 3=o
    const int unit = w * 16 + unit_local;      // global hidden unit 0..255
    const int grow = gate * 256 + unit;        // global gate row 0..1023
    const int kbase = kq * 64;

    // ---- one-time: weights -> fp32 registers (64 + 64 VGPRs) ----
    float whh[64], wih[64];
    {
        const float* p = Whh + (size_t)grow * 256 + kbase;
        #pragma unroll
        for (int j = 0; j < 64; j += 4) {
            float4 q = *(const float4*)(p + j);
            whh[j] = q.x; whh[j+1] = q.y; whh[j+2] = q.z; whh[j+3] = q.w;
        }
        p = Wih + (size_t)grow * 256 + kbase;
        #pragma unroll
        for (int j = 0; j < 64; j += 4) {
            float4 q = *(const float4*)(p + j);
            wih[j] = q.x; wih[j+1] = q.y; wih[j+2] = q.z; wih[j+3] = q.w;
        }
    }
    const float bias = bih[grow] + bhh[grow];
    const bool owner = ((lane & 15) == 0);   // kq==0 && gate==0 -> owns `unit`

    __shared__ float4 lds_h4[64];       // full h vector, fp32
    __shared__ float4 lds_e4[2][64];    // double-buffered embedding row, fp32

    // init: publish h=0 with tag 0 into parity-0 buffer (poison 0xAA.. never matches a tag)
    if (owner)
        __hip_atomic_store(hbuf + unit, 0ull, __ATOMIC_RELAXED, __HIP_MEMORY_SCOPE_AGENT);
    // preload embedding row for t=0
    if (tid < 64) {
        int tk = tokens[0];
        lds_e4[0][tid] = *(const float4*)(emb + (size_t)tk * 256 + tid * 4);
    }
    float c = 0.0f;
    __syncthreads();

    for (int t = 0; t < T_STEPS; ++t) {
        // prefetch next embedding row (h-independent; hides under spin-wait)
        if (tid < 64 && t + 1 < T_STEPS) {
            int tk = tokens[t + 1];
            lds_e4[(t + 1) & 1][tid] = *(const float4*)(emb + (size_t)tk * 256 + tid * 4);
        }
        // input contribution: wih . emb_t (h-independent)
        float acc = 0.0f;
        {
            const float4* eb = &lds_e4[t & 1][kq * 16];
            #pragma unroll
            for (int i = 0; i < 16; ++i) {
                float4 v = eb[i];
                acc = fmaf(wih[4*i+0], v.x, acc);
                acc = fmaf(wih[4*i+1], v.y, acc);
                acc = fmaf(wih[4*i+2], v.z, acc);
                acc = fmaf(wih[4*i+3], v.w, acc);
            }
        }
        // spin for h_{t-1}: one u64 load carries (value, tag) atomically
        {
            const unsigned long long* hb = hbuf + (size_t)(t & 1) * 256;
            unsigned long long p;
            do {
                p = __hip_atomic_load(hb + tid, __ATOMIC_RELAXED, __HIP_MEMORY_SCOPE_AGENT);
            } while ((unsigned int)(p >> 32) != (unsigned int)t);
            union { unsigned int i; float f; } hv; hv.i = (unsigned int)p;
            ((float*)lds_h4)[tid] = hv.f;
        }
        __syncthreads();
        // recurrent contribution: whh . h  (wave-broadcast LDS reads)
        {
            const float4* hb4 = &lds_h4[kq * 16];
            #pragma unroll
            for (int i = 0; i < 16; ++i) {
                float4 v = hb4[i];
                acc = fmaf(whh[4*i+0], v.x, acc);
                acc = fmaf(whh[4*i+1], v.y, acc);
                acc = fmaf(whh[4*i+2], v.z, acc);
                acc = fmaf(whh[4*i+3], v.w, acc);
            }
        }
        // reduce across the 4 k-quarter lanes (same row)
        acc += __shfl_xor(acc, 1, 64);
        acc += __shfl_xor(acc, 2, 64);
        acc += bias;
        // gather the 4 gate preactivations of this unit to the owner lane
        const int base = lane & 48;
        float g_i = __shfl(acc, base + 0,  64);
        float g_f = __shfl(acc, base + 4,  64);
        float g_c = __shfl(acc, base + 8,  64);
        float g_o = __shfl(acc, base + 12, 64);
        if (owner) {
            float iv = sigm(g_i), fv = sigm(g_f);
            float gv = tanh_fast(g_c), ov = sigm(g_o);
            c = fmaf(fv, c, iv * gv);
            float h = ov * tanh_fast(c);
            union { unsigned int i; float f; } u; u.f = h;
            unsigned long long pk =
                (((unsigned long long)(unsigned int)(t + 1)) << 32) | (unsigned long long)u.i;
            __hip_atomic_store(hbuf + (size_t)((t + 1) & 1) * 256 + unit, pk,
                               __ATOMIC_RELAXED, __HIP_MEMORY_SCOPE_AGENT);
            out[(size_t)t * HID + unit] = h;
            if (t == T_STEPS - 1) {
                out[(size_t)T_STEPS * HID + unit]       = h;  // h_last
                out[(size_t)T_STEPS * HID + HID + unit] = c;  // c_last
            }
        }
        __syncthreads();
    }
}

extern "C" void kernel_launch(void* const* d_in, const int* in_sizes, int n_in,
                              void* d_out, int out_size, void* d_ws, size_t ws_size,
                              hipStream_t stream) {
    const int*   tokens = (const int*)d_in[0];
    const float* emb    = (const float*)d_in[1];
    const float* Wih    = (const float*)d_in[2];
    const float* Whh    = (const float*)d_in[3];
    const float* bih    = (const float*)d_in[4];
    const float* bhh    = (const float*)d_in[5];
    float* out = (float*)d_out;
    unsigned long long* hbuf = (unsigned long long*)d_ws;   // 4 KB: [2][256] u64

    lstm_scan<<<NWG, THREADS, 0, stream>>>(tokens, emb, Wih, Whh, bih, bhh, out, hbuf);
}

// Round 3
// 12709.149 us; speedup vs baseline: 1.3453x; 1.3453x over previous
//
#include <hip/hip_runtime.h>
#include <hip/hip_bf16.h>

#define T_STEPS 8192
#define HID 256
#define NWG 16        // workgroups; each owns 16 hidden units (64 gate rows)
#define THREADS 256   // 4 waves; lane=(row, k-quarter): 64 rows x 4 k-quarters

__device__ __forceinline__ float sigm(float x) { return 1.0f / (1.0f + __expf(-x)); }
// 2/(1+e^-2x)-1 is inf-safe at both ends
__device__ __forceinline__ float tanh_fast(float x) { return 2.0f / (1.0f + __expf(-2.0f * x)) - 1.0f; }

__global__ __launch_bounds__(THREADS, 1)
void lstm_scan(const int* __restrict__ tokens,
               const float* __restrict__ emb,    // [V,256] fp32
               const float* __restrict__ Wih,    // [1024,256] fp32
               const float* __restrict__ Whh,    // [1024,256] fp32
               const float* __restrict__ bih,    // [1024]
               const float* __restrict__ bhh,    // [1024]
               float* __restrict__ out,          // [T*256 + 256 + 256] fp32
               unsigned long long* __restrict__ hbuf)  // [2][256] (h fp32, tag u32)
{
    const int tid  = threadIdx.x;
    const int w    = blockIdx.x;       // 0..15
    const int lane = tid & 63;
    const int wave = tid >> 6;         // 0..3
    const int rl   = lane >> 2;        // row-within-wave 0..15
    const int kq   = lane & 3;         // k-quarter 0..3
    const int r_wg = wave * 16 + rl;   // local gate-row 0..63
    const int unit_local = r_wg >> 2;  // 0..15
    const int gate = r_wg & 3;         // 0=i 1=f 2=cell 3=o
    const int unit = w * 16 + unit_local;      // global hidden unit 0..255
    const int grow = gate * 256 + unit;        // global gate row 0..1023
    const int kbase = kq * 64;

    // ---- one-time: weights -> fp32 registers (64 + 64 VGPRs) ----
    float whh[64], wih[64];
    {
        const float* p = Whh + (size_t)grow * 256 + kbase;
        #pragma unroll
        for (int j = 0; j < 64; j += 4) {
            float4 q = *(const float4*)(p + j);
            whh[j] = q.x; whh[j+1] = q.y; whh[j+2] = q.z; whh[j+3] = q.w;
        }
        p = Wih + (size_t)grow * 256 + kbase;
        #pragma unroll
        for (int j = 0; j < 64; j += 4) {
            float4 q = *(const float4*)(p + j);
            wih[j] = q.x; wih[j+1] = q.y; wih[j+2] = q.z; wih[j+3] = q.w;
        }
    }
    const float bias = bih[grow] + bhh[grow];
    const bool owner = ((lane & 15) == 0);   // kq==0 && gate==0 -> owns `unit`

    // padded: row q at float4-index q*17 -> bank starts (4i+4q)%32, conflict-free
    __shared__ float4 lds_h4[4][17];
    __shared__ float4 lds_e4[2][4][17];

    // init: publish h=0 with tag 0 into parity-0 buffer (poison 0xAA.. never matches a tag)
    if (owner)
        __hip_atomic_store(hbuf + unit, 0ull, __ATOMIC_RELAXED, __HIP_MEMORY_SCOPE_AGENT);
    // preload embedding row for t=0 (wave 1)
    if (wave == 1) {
        int tk = tokens[0];
        float4 e = *(const float4*)(emb + (size_t)tk * 256 + lane * 4);
        lds_e4[0][lane >> 4][lane & 15] = e;
    }
    float c = 0.0f;
    const float act_scale = (gate == 2) ? 2.0f : 1.0f;   // tanh vs sigmoid, single-exp form
    const float act_off   = (gate == 2) ? 1.0f : 0.0f;
    __syncthreads();

    for (int t = 0; t < T_STEPS; ++t) {
        // wave 1: prefetch next embedding row (h-independent, off critical wave)
        if (wave == 1) {
            int tk = tokens[(t + 1 < T_STEPS) ? t + 1 : t];
            float4 e = *(const float4*)(emb + (size_t)tk * 256 + lane * 4);
            lds_e4[(t + 1) & 1][lane >> 4][lane & 15] = e;
        }
        // input contribution: wih . emb_t (h-independent, overlaps publish latency)
        float acc = 0.0f;
        {
            const float4* eb = lds_e4[t & 1][kq];
            #pragma unroll
            for (int i = 0; i < 16; ++i) {
                float4 v = eb[i];
                acc = fmaf(wih[4*i+0], v.x, acc);
                acc = fmaf(wih[4*i+1], v.y, acc);
                acc = fmaf(wih[4*i+2], v.z, acc);
                acc = fmaf(wih[4*i+3], v.w, acc);
            }
        }
        // wave 0 alone polls all 256 (h, tag) pairs: 4 per lane
        if (wave == 0) {
            const unsigned long long* hb = hbuf + (size_t)(t & 1) * 256 + lane * 4;
            unsigned long long p0, p1, p2, p3;
            const unsigned int tt = (unsigned int)t;
            for (;;) {
                p0 = __hip_atomic_load(hb + 0, __ATOMIC_RELAXED, __HIP_MEMORY_SCOPE_AGENT);
                p1 = __hip_atomic_load(hb + 1, __ATOMIC_RELAXED, __HIP_MEMORY_SCOPE_AGENT);
                p2 = __hip_atomic_load(hb + 2, __ATOMIC_RELAXED, __HIP_MEMORY_SCOPE_AGENT);
                p3 = __hip_atomic_load(hb + 3, __ATOMIC_RELAXED, __HIP_MEMORY_SCOPE_AGENT);
                if ((unsigned int)(p0 >> 32) == tt && (unsigned int)(p1 >> 32) == tt &&
                    (unsigned int)(p2 >> 32) == tt && (unsigned int)(p3 >> 32) == tt)
                    break;
            }
            union { unsigned int i; float f; } a, b, cc, d;
            a.i = (unsigned int)p0; b.i = (unsigned int)p1;
            cc.i = (unsigned int)p2; d.i = (unsigned int)p3;
            lds_h4[lane >> 4][lane & 15] = make_float4(a.f, b.f, cc.f, d.f);
        }
        __syncthreads();   // the only barrier per step
        // recurrent contribution: whh . h (conflict-free padded reads)
        {
            const float4* hb4 = lds_h4[kq];
            #pragma unroll
            for (int i = 0; i < 16; ++i) {
                float4 v = hb4[i];
                acc = fmaf(whh[4*i+0], v.x, acc);
                acc = fmaf(whh[4*i+1], v.y, acc);
                acc = fmaf(whh[4*i+2], v.z, acc);
                acc = fmaf(whh[4*i+3], v.w, acc);
            }
        }
        // butterfly reduce across the 4 k-quarter lanes -> all hold full row sum
        acc += __shfl_xor(acc, 1, 64);
        acc += __shfl_xor(acc, 2, 64);
        acc += bias;
        // apply each gate's nonlinearity IN PARALLEL before gathering
        float e  = __expf(-act_scale * acc);
        float av = act_scale / (1.0f + e) - act_off;   // sigm for gates 0/1/3, tanh for 2
        // gather activated gate values of this unit to the owner lane
        const int base = lane & 48;
        float fv = __shfl(av, base + 4,  64);
        float gv = __shfl(av, base + 8,  64);
        float ov = __shfl(av, base + 12, 64);
        if (owner) {
            c = fmaf(fv, c, av * gv);                 // av == i-gate on owner
            float h = ov * tanh_fast(c);              // single serial transcendental
            union { unsigned int i; float f; } u; u.f = h;
            unsigned long long pk =
                (((unsigned long long)(unsigned int)(t + 1)) << 32) | (unsigned long long)u.i;
            __hip_atomic_store(hbuf + (size_t)((t + 1) & 1) * 256 + unit, pk,
                               __ATOMIC_RELAXED, __HIP_MEMORY_SCOPE_AGENT);
            out[(size_t)t * HID + unit] = h;
            if (t == T_STEPS - 1) {
                out[(size_t)T_STEPS * HID + unit]       = h;  // h_last
                out[(size_t)T_STEPS * HID + HID + unit] = c;  // c_last
            }
        }
        // no trailing barrier: spin discipline proves no WG-internal LDS race
    }
}

extern "C" void kernel_launch(void* const* d_in, const int* in_sizes, int n_in,
                              void* d_out, int out_size, void* d_ws, size_t ws_size,
                              hipStream_t stream) {
    const int*   tokens = (const int*)d_in[0];
    const float* emb    = (const float*)d_in[1];
    const float* Wih    = (const float*)d_in[2];
    const float* Whh    = (const float*)d_in[3];
    const float* bih    = (const float*)d_in[4];
    const float* bhh    = (const float*)d_in[5];
    float* out = (float*)d_out;
    unsigned long long* hbuf = (unsigned long long*)d_ws;   // 4 KB: [2][256] u64

    lstm_scan<<<NWG, THREADS, 0, stream>>>(tokens, emb, Wih, Whh, bih, bhh, out, hbuf);
}